// Round 13
// baseline (705.162 us; speedup 1.0000x reference)
//
#include <hip/hip_runtime.h>
#include <hip/hip_bf16.h>
#include <math.h>

// Problem dims
#define BB   4
#define TT   12
#define NN   307
#define SS   11
#define HH   64
#define NHH  4
#define EMB  152
#define ROWS 13508          // B*S*N
#define NBS  44             // B*S
#define NBT  48             // B*T
#define NP   320            // padded node count
#define EP   160            // padded embedding dim
#define KLP  24             // LDS K pitch (shorts) in attn
#define VLP  336            // LDS V^T pitch (shorts) in attn
#define PLP  40             // LDS P chunk pitch (shorts) in attn
#define HCP  264            // LDS hidden chunk pitch (shorts)
#define HLP  72             // LDS h1/z chunk pitch (shorts)

typedef short short8 __attribute__((ext_vector_type(8)));   // 8 bf16
typedef short short4a __attribute__((ext_vector_type(4)));  // 4 bf16
typedef float floatx4 __attribute__((ext_vector_type(4)));
#define MFMA_B16(a, b, c) __builtin_amdgcn_mfma_f32_16x16x32_bf16(a, b, c, 0, 0, 0)

__device__ __forceinline__ float wave_sum(float v) {
#pragma unroll
  for (int off = 32; off; off >>= 1) v += __shfl_xor(v, off);
  return v;
}
__device__ __forceinline__ short f2bf(float x) {
  __hip_bfloat16 h = __float2bfloat16(x);
  return *reinterpret_cast<short*>(&h);
}
// row r in (b,s,n) order -> flat offset of the 64-float row in Z ([b,n,s,h])
__device__ __forceinline__ long zoff_of_row(int r) {
  int bs = r / NN;
  int n = r - bs * NN;
  int b = bs / SS;
  int s = bs - b * SS;
  return (((long)b * NN + n) * SS + s) * 64;
}

// shared transpose helper (32x32 tile, fp32 -> bf16, optional scale)
__device__ __forceinline__ void xpose_tile(
    const float* __restrict__ src, __hip_bfloat16* __restrict__ dst,
    int K, int N, int bx, int by, float scale, float (*t)[33])
{
  int k0 = bx * 32, n0 = by * 32;
  int tx = threadIdx.x & 31, ty = threadIdx.x >> 5;
#pragma unroll
  for (int i = 0; i < 32; i += 8) {
    int k = k0 + ty + i, n = n0 + tx;
    if (k < K && n < N) t[ty + i][tx] = src[(long)k * N + n];
  }
  __syncthreads();
#pragma unroll
  for (int i = 0; i < 32; i += 8) {
    int n = n0 + ty + i, k = k0 + tx;
    if (k < K && n < N)
      dst[(long)n * K + k] = __float2bfloat16(t[tx][ty + i] * scale);
  }
}

// ---------------------------------------------------------------------------
// MEGA-PREP: all independent elementwise/transpose/pack work in ONE dispatch.
// Blocks [0,9600): embed -> XEMBb; [9600,10854): W_in transpose;
// [10854,10903): small-weight transposes + bias pack; [10903,18137):
// WGPT/adj packs + Z bias-init + C2 compute.
// ---------------------------------------------------------------------------
__global__ __launch_bounds__(256) void prep_kernel(
    const float* __restrict__ ori, const float* __restrict__ W_val,
    const float* __restrict__ b_val, const float* __restrict__ tod_emb,
    const float* __restrict__ dow_emb, const float* __restrict__ node_emb,
    const float* __restrict__ W_in,
    const float* __restrict__ Wq, const float* __restrict__ Wk,
    const float* __restrict__ Wv, const float* __restrict__ Wo,
    const float* __restrict__ Wf1, const float* __restrict__ Wf2,
    const float* __restrict__ bq, const float* __restrict__ bk,
    const float* __restrict__ bv,
    const float* __restrict__ Wg1, const float* __restrict__ Wg2,
    const float* __restrict__ adj, const float* __restrict__ adj_sem,
    const float* __restrict__ b_in,
    const float* __restrict__ coeff2, const float* __restrict__ W_ce,
    const float* __restrict__ b_ce,
    __hip_bfloat16* __restrict__ xe, __hip_bfloat16* __restrict__ WinT,
    __hip_bfloat16* __restrict__ WqkvT, __hip_bfloat16* __restrict__ WoT,
    __hip_bfloat16* __restrict__ Wf1T, __hip_bfloat16* __restrict__ Wf2T,
    float* __restrict__ bqkv,
    __hip_bfloat16* __restrict__ WGPT,
    __hip_bfloat16* __restrict__ adjb, __hip_bfloat16* __restrict__ adjsb,
    float* __restrict__ Z, float* __restrict__ C2)
{
  __shared__ float t[32][33];
  int blk = blockIdx.x;

  if (blk < 9600) {                 // ---- embedding ----
    int idx = blk * 256 + threadIdx.x;
    int c = idx % EP;
    int r = idx / EP;               // bt*NP + node
    int node = r % NP;
    int bt = r / NP;
    float v = 0.f;
    if (node < NN && c < EMB) {
      long orr = (long)bt * NN + node;
      if (c < 24) {
        const float* x = ori + orr * 3;
        v = x[0] * W_val[c] + x[1] * W_val[24 + c] + x[2] * W_val[48 + c] + b_val[c];
      } else if (c < 48) {
        float f = ori[orr * 3 + 1];
        f = f - floorf(f);
        int tod = (int)(f * 288.f);
        tod = min(max(tod, 0), 287);
        v = tod_emb[tod * 24 + (c - 24)];
      } else if (c < 72) {
        float f = ori[orr * 3 + 2];
        f = f - floorf(f);
        int dow = (int)(f * 7.f);
        dow = min(max(dow, 0), 6);
        v = dow_emb[dow * 24 + (c - 48)];
      } else {
        v = node_emb[node * 80 + (c - 72)];
      }
    }
    xe[idx] = __float2bfloat16(v);
  } else if (blk < 10854) {         // ---- W_in transpose (57 x 22 tiles) ----
    int q = blk - 9600;
    xpose_tile(W_in, WinT, 1824, 704, q % 57, q / 57, 1.f, t);
  } else if (blk < 10903) {         // ---- small-weight transposes + bias ----
    int b2 = blk - 10854;
    if (b2 == 48) {
      int th = threadIdx.x;
      if (th < 64) {
        bqkv[th] = bq[th] * 0.25f;  // score scale folded into q
        bqkv[64 + th] = bk[th];
        bqkv[128 + th] = bv[th];
      }
      return;
    }
    const float* src; __hip_bfloat16* dst;
    int K, N, bx, by; float scale = 1.f;
    if (b2 < 4)       { src = Wq;  dst = WqkvT;           K = 64;  N = 64;  bx = b2 & 1;        by = b2 >> 1;        scale = 0.25f; }
    else if (b2 < 8)  { src = Wk;  dst = WqkvT + 64 * 64; K = 64;  N = 64;  bx = (b2 - 4) & 1;  by = (b2 - 4) >> 1; }
    else if (b2 < 12) { src = Wv;  dst = WqkvT + 128 * 64;K = 64;  N = 64;  bx = (b2 - 8) & 1;  by = (b2 - 8) >> 1; }
    else if (b2 < 16) { src = Wo;  dst = WoT;             K = 64;  N = 64;  bx = (b2 - 12) & 1; by = (b2 - 12) >> 1; }
    else if (b2 < 32) { src = Wf1; dst = Wf1T;            K = 64;  N = 256; bx = (b2 - 16) % 2; by = (b2 - 16) / 2; }
    else              { src = Wf2; dst = Wf2T;            K = 256; N = 64;  bx = (b2 - 32) % 8; by = (b2 - 32) / 8; }
    xpose_tile(src, dst, K, N, bx, by, scale, t);
  } else {                          // ---- packs + Z init + C2 ----
    int b3 = blk - 10903;
    if (b3 < 80) {
      int idx = b3 * 256 + threadIdx.x;           // < 128*160
      int c = idx / EP, k = idx % EP;
      float v = 0.f;
      if (k < EMB) v = (c < 64) ? Wg1[k * 64 + c] : Wg2[k * 64 + (c - 64)];
      WGPT[idx] = __float2bfloat16(v);
    } else if (b3 < 480) {
      int idx = (b3 - 80) * 256 + threadIdx.x;    // < 320*320
      int m = idx / NP, k = idx % NP;
      float v1 = 0.f, v2 = 0.f;
      if (m < NN && k < NN) { v1 = adj[m * NN + k]; v2 = adj_sem[m * NN + k]; }
      adjb[idx] = __float2bfloat16(v1);
      adjsb[idx] = __float2bfloat16(v2);
    } else if (b3 < 3857) {
      int idx = (b3 - 480) * 256 + threadIdx.x;   // < 1228*704
      Z[idx] = b_in[idx % 704];
    } else {
      int idx = (b3 - 3857) * 256 + threadIdx.x;  // < 13508*64
      int row = idx >> 6, h = idx & 63;           // row = (b*N+n)*S + s
      float a0 = coeff2[(long)row * 2];
      float a1 = coeff2[(long)row * 2 + 1];
      C2[idx] = a0 * W_ce[h] + a1 * W_ce[64 + h] + b_ce[h];
    }
  }
}

// ---------------------------------------------------------------------------
// xg_mfma: XGT[bt, c(128), node(320)] = (XEMBb[bt] @ WGP)^T  (bf16 out)
// ---------------------------------------------------------------------------
__global__ __launch_bounds__(256) void xg_mfma(
    const __hip_bfloat16* __restrict__ XE, const __hip_bfloat16* __restrict__ WGPT,
    __hip_bfloat16* __restrict__ XGT)
{
  int bt = blockIdx.x;
  int tid = threadIdx.x, w = tid >> 6, l = tid & 63;
  int m0 = blockIdx.y * 64 + w * 16;      // node tile
  int cq = l & 15, rq = l >> 4;

  short8 af[5];
  const short* Ap = (const short*)XE + ((long)bt * NP + m0 + cq) * EP + rq * 8;
#pragma unroll
  for (int kk = 0; kk < 5; ++kk) af[kk] = *(const short8*)(Ap + kk * 32);

#pragma unroll
  for (int ct = 0; ct < 8; ++ct) {
    const short* Bp = (const short*)WGPT + (long)(ct * 16 + cq) * EP + rq * 8;
    floatx4 acc = {0.f, 0.f, 0.f, 0.f};
#pragma unroll
    for (int kk = 0; kk < 5; ++kk)
      acc = MFMA_B16(af[kk], *(const short8*)(Bp + kk * 32), acc);
    short4a pk;
#pragma unroll
    for (int r = 0; r < 4; ++r) pk[r] = f2bf(acc[r]);
    *(short4a*)((short*)XGT + ((long)bt * 128 + ct * 16 + cq) * NP + m0 + rq * 4) = pk;
  }
}

// ---------------------------------------------------------------------------
// gcn_mfma: GT[bt, node, 64] = relu( adj@XG1 + adjsem@XG2 + bg )  fp32 out
// ---------------------------------------------------------------------------
__global__ __launch_bounds__(256) void gcn_mfma(
    const __hip_bfloat16* __restrict__ XGT, const __hip_bfloat16* __restrict__ adjb,
    const __hip_bfloat16* __restrict__ adjsb, const float* __restrict__ bg,
    float* __restrict__ GT)
{
  int bt = blockIdx.x;
  int tid = threadIdx.x, w = tid >> 6, l = tid & 63;
  int n0 = blockIdx.y * 64;
  int cq = l & 15, rq = l >> 4;

  short8 a1[10], a2[10];
  const short* A1p = (const short*)XGT + ((long)bt * 128 + w * 16 + cq) * NP + rq * 8;
  const short* A2p = A1p + 64 * NP;
#pragma unroll
  for (int kk = 0; kk < 10; ++kk) {
    a1[kk] = *(const short8*)(A1p + kk * 32);
    a2[kk] = *(const short8*)(A2p + kk * 32);
  }

  float bgv[4];
#pragma unroll
  for (int r = 0; r < 4; ++r) bgv[r] = bg[w * 16 + rq * 4 + r];

#pragma unroll
  for (int nt = 0; nt < 4; ++nt) {
    const short* B1p = (const short*)adjb + (long)(n0 + nt * 16 + cq) * NP + rq * 8;
    const short* B2p = (const short*)adjsb + (long)(n0 + nt * 16 + cq) * NP + rq * 8;
    floatx4 acc = {0.f, 0.f, 0.f, 0.f};
#pragma unroll
    for (int kk = 0; kk < 10; ++kk) {
      acc = MFMA_B16(a1[kk], *(const short8*)(B1p + kk * 32), acc);
      acc = MFMA_B16(a2[kk], *(const short8*)(B2p + kk * 32), acc);
    }
    int node = n0 + nt * 16 + cq;
    if (node < NN) {
      float4 pk;
      pk.x = fmaxf(acc[0] + bgv[0], 0.f);
      pk.y = fmaxf(acc[1] + bgv[1], 0.f);
      pk.z = fmaxf(acc[2] + bgv[2], 0.f);
      pk.w = fmaxf(acc[3] + bgv[3], 0.f);
      *(float4*)(GT + (((long)bt * NP + node) * 64 + w * 16 + rq * 4)) = pk;
    }
  }
}

// ---------------------------------------------------------------------------
// x_in GEMM, bf16 MFMA, split-K=4, reads XEMBb directly (152 % 8 == 0).
// ---------------------------------------------------------------------------
__global__ __launch_bounds__(256) void gemm_xin(
    const __hip_bfloat16* __restrict__ XE, const __hip_bfloat16* __restrict__ BT,
    float* __restrict__ C)
{
  int tid = threadIdx.x, w = tid >> 6, l = tid & 63;
  int m0 = blockIdx.x * 64 + w * 16;
  int n0 = blockIdx.y * 64;
  int k0s = blockIdx.z * 480;
  int k0e = min(1824, k0s + 480);

  int cq = l & 15, rq = l >> 4;
  int arow = min(m0 + cq, 1227);
  int ab = arow / NN, an = arow - ab * NN;
  const short* Abase = (const short*)XE;
  const short* Bp = (const short*)BT + rq * 8;

  floatx4 acc[4] = {};
  for (int k0 = k0s; k0 < k0e; k0 += 32) {
    int kk = k0 + rq * 8;
    int t = kk / EMB;
    int c = kk - t * EMB;
    short8 a = *(const short8*)(Abase + (((long)(ab * TT + t)) * NP + an) * EP + c);
#pragma unroll
    for (int nt = 0; nt < 4; ++nt) {
      short8 b = *(const short8*)(Bp + (long)(n0 + nt * 16 + cq) * 1824 + k0);
      acc[nt] = MFMA_B16(a, b, acc[nt]);
    }
  }
#pragma unroll
  for (int nt = 0; nt < 4; ++nt) {
    int c = n0 + nt * 16 + cq;
#pragma unroll
    for (int r = 0; r < 4; ++r) {
      int row = m0 + rq * 4 + r;
      if (row < 1228) atomicAdd(&C[(long)row * 704 + c], acc[nt][r]);
    }
  }
}

// ---------------------------------------------------------------------------
// gp (GCN output head) + initial QKV projection in ONE dispatch.
// Blocks [0,307): gp, 4 (b,n) pairs per block (one per wave, wave-private).
// Blocks [307,527): qkv (reads Z fp32 directly).
// ---------------------------------------------------------------------------
__global__ __launch_bounds__(256) void gp_qkv(
    const float* __restrict__ GT, const float* __restrict__ Wgo,
    const float* __restrict__ bgo, const float* __restrict__ w_het,
    float* __restrict__ out,
    const float* __restrict__ Z, const __hip_bfloat16* __restrict__ WT,
    const float* __restrict__ bqkv,
    __hip_bfloat16* __restrict__ Qb, __hip_bfloat16* __restrict__ Kb,
    __hip_bfloat16* __restrict__ Vtb)
{
  __shared__ float buf[4][TT * 64];
  int blk = blockIdx.x;
  if (blk < 307) {
    int wave = threadIdx.x >> 6, lane = threadIdx.x & 63;
    int bn = blk * 4 + wave;        // 307*4 = 1228 exact
    int b = bn / NN, n = bn % NN;
    float* bw = buf[wave];
    for (int idx = lane; idx < TT * 64; idx += 64) {
      int t = idx >> 6, h = idx & 63;
      bw[idx] = GT[(((long)(b * TT + t)) * NP + n) * 64 + h];
    }
    // wave-private buffer: no barrier needed
    float acc[12] = {};
#pragma unroll
    for (int j = 0; j < 12; ++j) {
      int k = j * 64 + lane;
      float g = bw[k];
      const float* wr = Wgo + (long)k * 12;
#pragma unroll
      for (int o = 0; o < 12; ++o) acc[o] += g * wr[o];
    }
#pragma unroll
    for (int o = 0; o < 12; ++o) acc[o] = wave_sum(acc[o]);
    if (lane == 0) {
      float wh = w_het[0];
#pragma unroll
      for (int o = 0; o < 12; ++o)
        out[((long)b * 12 + o) * NN + n] = wh * (acc[o] + bgo[o]);
    }
  } else {
    int q = blk - 307;
    int bs = q / 5, mt = q % 5;
    int tid = threadIdx.x, w = tid >> 6, l = tid & 63;
    int m0 = mt * 64 + w * 16;
    int cq = l & 15, rq = l >> 4;
    int b = bs / SS, s = bs - b * SS;

    int node0 = m0 + cq;
    short8 a0 = {0, 0, 0, 0, 0, 0, 0, 0}, a1 = a0;
    if (node0 < NN) {
      const float* zp = Z + (((long)(b * NN + node0)) * SS + s) * 64 + rq * 8;
#pragma unroll
      for (int j = 0; j < 8; ++j) {
        a0[j] = f2bf(zp[j]);
        a1[j] = f2bf(zp[32 + j]);
      }
    }
#pragma unroll
    for (int nt = 0; nt < 12; ++nt) {
      const short* Bp = (const short*)WT + (long)(nt * 16 + cq) * 64 + rq * 8;
      floatx4 acc = {0.f, 0.f, 0.f, 0.f};
      acc = MFMA_B16(a0, *(const short8*)Bp, acc);
      acc = MFMA_B16(a1, *(const short8*)(Bp + 32), acc);
      int c = nt * 16 + cq;
      float bias = bqkv[c];
#pragma unroll
      for (int r = 0; r < 4; ++r) {
        int node = m0 + rq * 4 + r;
        if (node < NN) {
          __hip_bfloat16 v = __float2bfloat16(acc[r] + bias);
          if (c < 64)       Qb[((long)bs * NP + node) * 64 + c] = v;
          else if (c < 128) Kb[((long)bs * NP + node) * 64 + (c - 64)] = v;
          else              Vtb[((long)bs * 64 + (c - 128)) * NP + node] = v;
        }
      }
    }
  }
}

// ---------------------------------------------------------------------------
// MFMA attention (R6/R8 proven structure; 880 blocks).
// ---------------------------------------------------------------------------
__global__ __launch_bounds__(256) void attn_mfma(
    const __hip_bfloat16* __restrict__ Qb, const __hip_bfloat16* __restrict__ Kb,
    const __hip_bfloat16* __restrict__ Vtb, __hip_bfloat16* __restrict__ O)
{
  int bsh = blockIdx.x;           // bs*NH + head
  int head = bsh & 3;
  int bs = bsh >> 2;

  __shared__ __align__(16) short Kl[NP * KLP];
  __shared__ __align__(16) short Vl[16 * VLP];
  __shared__ __align__(16) short Pd[4][2][16 * PLP];

  int tid = threadIdx.x;
  const short* kg = (const short*)Kb + (long)bs * NP * 64 + head * 16;
  for (int ch = tid; ch < NP * 4; ch += 256) {
    int node = ch >> 2, part = (ch & 3) * 4;
    short4a kv = {0, 0, 0, 0};
    if (node < NN) kv = *(const short4a*)(kg + (long)node * 64 + part);
    *(short4a*)&Kl[node * KLP + part] = kv;
  }
  const short* vg = (const short*)Vtb + ((long)bs * 64 + head * 16) * NP;
  for (int ch = tid; ch < 16 * 80; ch += 256) {
    int d = ch / 80, k4 = (ch % 80) * 4;
    short4a vv = {0, 0, 0, 0};
    if (k4 + 3 < NN) {
      vv = *(const short4a*)(vg + (long)d * NP + k4);
    } else {
#pragma unroll
      for (int j = 0; j < 4; ++j)
        if (k4 + j < NN) vv[j] = vg[(long)d * NP + k4 + j];
    }
    *(short4a*)&Vl[d * VLP + k4] = vv;
  }
  __syncthreads();

  int wave = tid >> 6, lane = tid & 63;
  int m = lane & 15, quad = lane >> 4;
  int gg = blockIdx.y * 4 + wave;     // 16-query group, 0..19
  int q0 = gg * 16;
  int qv = q0 + m;

  const short8 z8 = {0, 0, 0, 0, 0, 0, 0, 0};
  const floatx4 zf = {0.f, 0.f, 0.f, 0.f};

  short8 qf = z8;
  if (quad < 2 && qv < NN)
    qf = *(const short8*)((const short*)Qb +
        ((long)bs * NP + qv) * 64 + head * 16 + quad * 8);

  short* Pw0 = &Pd[wave][0][0];
  short* Pw1 = &Pd[wave][1][0];

  float sum = 0.f;
  floatx4 oa = zf, ob = zf;

  for (int c = 0; c < 10; ++c) {
    short8 kf0 = z8, kf1 = z8;
    if (quad < 2) {
      kf0 = *(const short8*)&Kl[((2 * c) * 16 + m) * KLP + quad * 8];
      kf1 = *(const short8*)&Kl[((2 * c + 1) * 16 + m) * KLP + quad * 8];
    }
    floatx4 s0 = MFMA_B16(kf0, qf, zf);
    floatx4 s1 = MFMA_B16(kf1, qf, zf);

    float e0[4], e1[4];
#pragma unroll
    for (int j = 0; j < 4; ++j) {
      e0[j] = __expf(fminf(s0[j], 30.f));
      e1[j] = __expf(fminf(s1[j], 30.f));
    }
    if (c == 9) {
      if (quad == 0) e1[3] = 0.f;
      else { e1[0] = 0.f; e1[1] = 0.f; e1[2] = 0.f; e1[3] = 0.f; }
    }
    sum += e0[0] + e0[1] + e0[2] + e0[3] + e1[0] + e1[1] + e1[2] + e1[3];

    short4a p0, p1;
#pragma unroll
    for (int j = 0; j < 4; ++j) { p0[j] = f2bf(e0[j]); p1[j] = f2bf(e1[j]); }
    short* Pw = (c & 1) ? Pw1 : Pw0;
    *(short4a*)&Pw[m * PLP + quad * 4] = p0;
    *(short4a*)&Pw[m * PLP + 16 + quad * 4] = p1;

    short8 pf = *(const short8*)&Pw[m * PLP + quad * 8];
    short8 vf = *(const short8*)&Vl[m * VLP + c * 32 + quad * 8];
    if (c & 1) ob = MFMA_B16(vf, pf, ob);
    else       oa = MFMA_B16(vf, pf, oa);
  }

  sum += __shfl_xor(sum, 16);
  sum += __shfl_xor(sum, 32);
  float inv = 1.f / sum;

  if (qv < NN) {
    short4a pk;
#pragma unroll
    for (int r = 0; r < 4; ++r) pk[r] = f2bf((oa[r] + ob[r]) * inv);
    *(short4a*)((short*)O + ((long)bs * NN + qv) * 64 + head * 16 + quad * 4) = pk;
  }
}

// ---------------------------------------------------------------------------
// Fused scan epilogue + next-iter QKV (+ final LN/end_conv at iter SS-1).
// 64-thread blocks, grid 845.
// ---------------------------------------------------------------------------
__global__ __launch_bounds__(64) void block_step2(
    const __hip_bfloat16* __restrict__ A, const __hip_bfloat16* __restrict__ WoT,
    const float* __restrict__ bo, const float* __restrict__ ln1g,
    const float* __restrict__ ln1b,
    const __hip_bfloat16* __restrict__ Wf1T, const float* __restrict__ bf1,
    const __hip_bfloat16* __restrict__ Wf2T, const float* __restrict__ bf2,
    const float* __restrict__ ln2g, const float* __restrict__ ln2b,
    const float* __restrict__ C2, const float* __restrict__ W_tp2,
    const float* __restrict__ b_tp2,
    const __hip_bfloat16* __restrict__ WqkvT, const float* __restrict__ bqkv,
    const float* __restrict__ lnf_g, const float* __restrict__ lnf_b,
    const float* __restrict__ W_end, const float* __restrict__ b_end,
    const float* __restrict__ w_acl, float* __restrict__ out,
    float* __restrict__ Z,
    __hip_bfloat16* __restrict__ Qn, __hip_bfloat16* __restrict__ Kn,
    __hip_bfloat16* __restrict__ Vtn, int iter)
{
  __shared__ __align__(16) short Hl[16 * HLP];   // h1 / zn chunk
  __shared__ __align__(16) short Hc[16 * HCP];   // hidden chunk

  int l = threadIdx.x;
  int m0 = blockIdx.x * 16;
  int cq = l & 15, rq = l >> 4;

  // ---- Wo GEMM ----
  const short* Ap = (const short*)A + (long)(m0 + cq) * 64 + rq * 8;
  short8 a0 = *(const short8*)Ap;
  short8 a1 = *(const short8*)(Ap + 32);

  float x[4][4];                      // [nt][r]: row m0+rq*4+r, col nt*16+cq
#pragma unroll
  for (int nt = 0; nt < 4; ++nt) {
    const short* Bp = (const short*)WoT + (long)(nt * 16 + cq) * 64 + rq * 8;
    floatx4 acc = {0.f, 0.f, 0.f, 0.f};
    acc = MFMA_B16(a0, *(const short8*)Bp, acc);
    acc = MFMA_B16(a1, *(const short8*)(Bp + 32), acc);
    float bv = bo[nt * 16 + cq];
#pragma unroll
    for (int r = 0; r < 4; ++r) x[nt][r] = acc[r] + bv;
  }
  // residual from Z
  int rows[4]; bool val[4]; long zov[4];
#pragma unroll
  for (int r = 0; r < 4; ++r) {
    rows[r] = m0 + rq * 4 + r;
    val[r] = rows[r] < ROWS;
    zov[r] = zoff_of_row(min(rows[r], ROWS - 1));
#pragma unroll
    for (int nt = 0; nt < 4; ++nt) x[nt][r] += Z[zov[r] + nt * 16 + cq];
  }
  float g1v[4], b1v[4], g2v[4], b2v[4], f2v[4];
#pragma unroll
  for (int nt = 0; nt < 4; ++nt) {
    g1v[nt] = ln1g[nt * 16 + cq];
    b1v[nt] = ln1b[nt * 16 + cq];
    g2v[nt] = ln2g[nt * 16 + cq];
    b2v[nt] = ln2b[nt * 16 + cq];
    f2v[nt] = bf2[nt * 16 + cq];
  }

  // ---- LN1 -> h1 (regs + LDS chunk) ----
  float h1[4][4];
#pragma unroll
  for (int r = 0; r < 4; ++r) {
    float s = x[0][r] + x[1][r] + x[2][r] + x[3][r];
#pragma unroll
    for (int off = 1; off <= 8; off <<= 1) s += __shfl_xor(s, off);
    float mean = s * (1.f / 64.f);
    float vs = 0.f;
#pragma unroll
    for (int nt = 0; nt < 4; ++nt) {
      float d = x[nt][r] - mean;
      vs += d * d;
    }
#pragma unroll
    for (int off = 1; off <= 8; off <<= 1) vs += __shfl_xor(vs, off);
    float rstd = rsqrtf(vs * (1.f / 64.f) + 1e-5f);
#pragma unroll
    for (int nt = 0; nt < 4; ++nt) {
      float h = (x[nt][r] - mean) * rstd * g1v[nt] + b1v[nt];
      h1[nt][r] = h;
      Hl[(rq * 4 + r) * HLP + nt * 16 + cq] = f2bf(h);
    }
  }

  // ---- FFN phase A: hidden = relu(h1@Wf1+bf1) -> LDS hidden chunk ----
  short8 ha0 = *(const short8*)&Hl[cq * HLP + rq * 8];
  short8 ha1 = *(const short8*)&Hl[cq * HLP + 32 + rq * 8];
#pragma unroll
  for (int ht = 0; ht < 16; ++ht) {
    const short* Bp = (const short*)Wf1T + (long)(ht * 16 + cq) * 64 + rq * 8;
    floatx4 acc = {0.f, 0.f, 0.f, 0.f};
    acc = MFMA_B16(ha0, *(const short8*)Bp, acc);
    acc = MFMA_B16(ha1, *(const short8*)(Bp + 32), acc);
    float bv = bf1[ht * 16 + cq];
#pragma unroll
    for (int r = 0; r < 4; ++r)
      Hc[(rq * 4 + r) * HCP + ht * 16 + cq] = f2bf(fmaxf(acc[r] + bv, 0.f));
  }

  // ---- FFN phase B: x = h1 + hidden@Wf2 + bf2 ----
#pragma unroll
  for (int nt = 0; nt < 4; ++nt) {
    const short* Bp = (const short*)Wf2T + (long)(nt * 16 + cq) * 256 + rq * 8;
    floatx4 acc = {0.f, 0.f, 0.f, 0.f};
#pragma unroll
    for (int kk = 0; kk < 8; ++kk) {
      short8 pf = *(const short8*)&Hc[cq * HCP + kk * 32 + rq * 8];
      acc = MFMA_B16(pf, *(const short8*)(Bp + kk * 32), acc);
    }
#pragma unroll
    for (int r = 0; r < 4; ++r) x[nt][r] = h1[nt][r] + acc[r] + f2v[nt];
  }

  // ---- LN2 + tanh + Euler update; zn -> Z, LDS chunk, and x (for final) ----
#pragma unroll
  for (int r = 0; r < 4; ++r) {
    if (!val[r]) continue;
    float s = x[0][r] + x[1][r] + x[2][r] + x[3][r];
#pragma unroll
    for (int off = 1; off <= 8; off <<= 1) s += __shfl_xor(s, off);
    float mean = s * (1.f / 64.f);
    float vs = 0.f;
#pragma unroll
    for (int nt = 0; nt < 4; ++nt) {
      float d = x[nt][r] - mean;
      vs += d * d;
    }
#pragma unroll
    for (int off = 1; off <= 8; off <<= 1) vs += __shfl_xor(vs, off);
    float rstd = rsqrtf(vs * (1.f / 64.f) + 1e-5f);

    int bs = rows[r] / NN;
    int node = rows[r] - bs * NN;
    int b = bs / SS, s1 = bs - b * SS;
    long bn = (long)b * NN + node;
    float wtp[SS];
#pragma unroll
    for (int s2 = 0; s2 < SS; ++s2)
      wtp[s2] = W_tp2[s2 * (SS * SS) + s1 * SS + iter];
    float btp = b_tp2[s1 * SS + iter];

#pragma unroll
    for (int nt = 0; nt < 4; ++nt) {
      int col = nt * 16 + cq;
      float t = tanhf((x[nt][r] - mean) * rstd * g2v[nt] + b2v[nt]);
      float acc = btp;
#pragma unroll
      for (int s2 = 0; s2 < SS; ++s2)
        acc += C2[(bn * SS + s2) * 64 + col] * wtp[s2];
      float zn = Z[zov[r] + col] + t * acc;
      Z[zov[r] + col] = zn;
      Hl[(rq * 4 + r) * HLP + col] = f2bf(zn);   // for QKV below
      x[nt][r] = zn;                             // for final below
    }
  }

  if (iter < SS - 1) {
    // ---- QKV for next iter (double-buffered outputs) ----
    short8 za0 = *(const short8*)&Hl[cq * HLP + rq * 8];
    short8 za1 = *(const short8*)&Hl[cq * HLP + 32 + rq * 8];
#pragma unroll
    for (int nt = 0; nt < 12; ++nt) {
      const short* Bp = (const short*)WqkvT + (long)(nt * 16 + cq) * 64 + rq * 8;
      floatx4 acc = {0.f, 0.f, 0.f, 0.f};
      acc = MFMA_B16(za0, *(const short8*)Bp, acc);
      acc = MFMA_B16(za1, *(const short8*)(Bp + 32), acc);
      int c = nt * 16 + cq;
      float bias = bqkv[c];
#pragma unroll
      for (int r = 0; r < 4; ++r) {
        int row = m0 + rq * 4 + r;
        if (row < ROWS) {
          int bs = row / NN;
          int node = row - bs * NN;
          __hip_bfloat16 v = __float2bfloat16(acc[r] + bias);
          if (c < 64)       Qn[((long)bs * NP + node) * 64 + c] = v;
          else if (c < 128) Kn[((long)bs * NP + node) * 64 + (c - 64)] = v;
          else              Vtn[((long)bs * 64 + (c - 128)) * NP + node] = v;
        }
      }
    }
  } else {
    // ---- final: zT = LN(zn; lnf); out += w_acl*(zT@W_end + b_end) ----
    float gf[4], bf[4];
#pragma unroll
    for (int nt = 0; nt < 4; ++nt) {
      gf[nt] = lnf_g[nt * 16 + cq];
      bf[nt] = lnf_b[nt * 16 + cq];
    }
    float wa = w_acl[0];
#pragma unroll
    for (int r = 0; r < 4; ++r) {
      if (!val[r]) continue;
      int bs = rows[r] / NN;
      if (bs % SS != SS - 1) continue;          // only last segment rows
      int node = rows[r] - bs * NN;
      int b = bs / SS;
      float s = x[0][r] + x[1][r] + x[2][r] + x[3][r];
#pragma unroll
      for (int off = 1; off <= 8; off <<= 1) s += __shfl_xor(s, off);
      float mean = s * (1.f / 64.f);
      float vs = 0.f;
#pragma unroll
      for (int nt = 0; nt < 4; ++nt) {
        float d = x[nt][r] - mean;
        vs += d * d;
      }
#pragma unroll
      for (int off = 1; off <= 8; off <<= 1) vs += __shfl_xor(vs, off);
      float rstd = rsqrtf(vs * (1.f / 64.f) + 1e-5f);
      float zT[4];
#pragma unroll
      for (int nt = 0; nt < 4; ++nt)
        zT[nt] = (x[nt][r] - mean) * rstd * gf[nt] + bf[nt];
#pragma unroll
      for (int o = 0; o < 12; ++o) {
        float p = 0.f;
#pragma unroll
        for (int nt = 0; nt < 4; ++nt)
          p += zT[nt] * W_end[(nt * 16 + cq) * 12 + o];
#pragma unroll
        for (int off = 1; off <= 8; off <<= 1) p += __shfl_xor(p, off);
        if (cq == 0) {
          long oi = ((long)b * 12 + o) * NN + node;
          out[oi] = out[oi] + wa * (p + b_end[o]);
        }
      }
    }
  }
}

// ---------------------------------------------------------------------------
extern "C" void kernel_launch(void* const* d_in, const int* in_sizes, int n_in,
                              void* d_out, int out_size, void* d_ws, size_t ws_size,
                              hipStream_t stream)
{
  (void)in_sizes; (void)n_in; (void)out_size; (void)ws_size;

  const float* ori_x    = (const float*)d_in[0];
  const float* coeff2   = (const float*)d_in[2];
  const float* W_val    = (const float*)d_in[5];
  const float* b_val    = (const float*)d_in[6];
  const float* tod_emb  = (const float*)d_in[7];
  const float* dow_emb  = (const float*)d_in[8];
  const float* node_emb = (const float*)d_in[9];
  const float* W_in     = (const float*)d_in[10];
  const float* b_in     = (const float*)d_in[11];
  const float* W_ce     = (const float*)d_in[12];
  const float* b_ce     = (const float*)d_in[13];
  const float* W_tp2    = (const float*)d_in[14];
  const float* b_tp2    = (const float*)d_in[15];
  const float* Wq = (const float*)d_in[20];
  const float* Wk = (const float*)d_in[21];
  const float* Wv = (const float*)d_in[22];
  const float* Wo = (const float*)d_in[23];
  const float* bq = (const float*)d_in[24];
  const float* bk = (const float*)d_in[25];
  const float* bv = (const float*)d_in[26];
  const float* bo = (const float*)d_in[27];
  const float* ln1_g = (const float*)d_in[28];
  const float* ln1_b = (const float*)d_in[29];
  const float* Wf1   = (const float*)d_in[30];
  const float* bf1   = (const float*)d_in[31];
  const float* Wf2   = (const float*)d_in[32];
  const float* bf2   = (const float*)d_in[33];
  const float* ln2_g = (const float*)d_in[34];
  const float* ln2_b = (const float*)d_in[35];
  const float* lnf_g = (const float*)d_in[36];
  const float* lnf_b = (const float*)d_in[37];
  const float* W_end = (const float*)d_in[38];
  const float* b_end = (const float*)d_in[39];
  const float* w_acl = (const float*)d_in[40];
  const float* w_het = (const float*)d_in[41];
  const float* adj     = (const float*)d_in[42];
  const float* adj_sem = (const float*)d_in[43];
  const float* Wg1 = (const float*)d_in[44];
  const float* Wg2 = (const float*)d_in[45];
  const float* bg  = (const float*)d_in[46];
  const float* Wgo = (const float*)d_in[47];
  const float* bgo = (const float*)d_in[48];
  float* out = (float*)d_out;
  float* ws  = (float*)d_ws;

  const int QSET = 450560;            // floats per Q/K/V tensor (44*320*64 bf16)

  // ---- workspace layout (float offsets, 16-float aligned) ----
  float* Z  = ws;                                // 864512
  float* C2 = ws + 864512;                       // 864512
  __hip_bfloat16* WinT  = (__hip_bfloat16*)(ws + 1729024);   // 704*1824 bf16
  __hip_bfloat16* WqkvT = (__hip_bfloat16*)(ws + 2371072);   // 192*64
  __hip_bfloat16* WoT   = (__hip_bfloat16*)(ws + 2377216);   // 64*64
  __hip_bfloat16* Wf1T  = (__hip_bfloat16*)(ws + 2379264);   // 256*64
  __hip_bfloat16* Wf2T  = (__hip_bfloat16*)(ws + 2387456);   // 64*256
  float* BQKV = ws + 2395648;                    // 192 (+pad)
  // double-buffered QKV sets
  __hip_bfloat16* QA  = (__hip_bfloat16*)(ws + 2395856);
  __hip_bfloat16* KA  = (__hip_bfloat16*)(ws + 2395856 + QSET);
  __hip_bfloat16* VA  = (__hip_bfloat16*)(ws + 2395856 + 2 * QSET);
  __hip_bfloat16* QB2 = (__hip_bfloat16*)(ws + 2395856 + 3 * QSET);
  __hip_bfloat16* KB2 = (__hip_bfloat16*)(ws + 2395856 + 4 * QSET);
  __hip_bfloat16* VB2 = (__hip_bfloat16*)(ws + 2395856 + 5 * QSET);
  float* POOL = ws + 2395856 + 6 * QSET;         // = ws + 5099216
  // phase 1
  __hip_bfloat16* XEMBb = (__hip_bfloat16*)POOL;             // 48*320*160
  __hip_bfloat16* XGT   = (__hip_bfloat16*)(POOL + 1228800); // 48*128*320
  float* GT             = POOL + 2211840;                    // 48*320*64 fp32
  __hip_bfloat16* ADJB  = (__hip_bfloat16*)(POOL + 3194880); // 320*320
  __hip_bfloat16* ADJSB = (__hip_bfloat16*)(POOL + 3246080); // 320*320
  __hip_bfloat16* WGPT  = (__hip_bfloat16*)(POOL + 3297280); // 128*160
  // phase 2 (overlays phase 1)
  __hip_bfloat16* Obf   = (__hip_bfloat16*)POOL;             // 13568*64

  // ---- phase 1: 5 dispatches ----
  prep_kernel<<<dim3(18137), dim3(256), 0, stream>>>(
      ori_x, W_val, b_val, tod_emb, dow_emb, node_emb, W_in,
      Wq, Wk, Wv, Wo, Wf1, Wf2, bq, bk, bv,
      Wg1, Wg2, adj, adj_sem, b_in, coeff2, W_ce, b_ce,
      XEMBb, WinT, WqkvT, WoT, Wf1T, Wf2T, BQKV,
      WGPT, ADJB, ADJSB, Z, C2);
  gemm_xin<<<dim3(20, 11, 4), dim3(256), 0, stream>>>(XEMBb, WinT, Z);
  xg_mfma<<<dim3(NBT, 5), dim3(256), 0, stream>>>(XEMBb, WGPT, XGT);
  gcn_mfma<<<dim3(NBT, 5), dim3(256), 0, stream>>>(XGT, ADJB, ADJSB, bg, GT);
  gp_qkv<<<dim3(527), dim3(256), 0, stream>>>(
      GT, Wgo, bgo, w_het, out, Z, WqkvT, BQKV, QA, KA, VA);

  // ---- phase 2: Euler scan, 2 dispatches per step (final fused in last) ----
  for (int i = 0; i < SS; ++i) {
    __hip_bfloat16 *Qr, *Kr, *Vr, *Qw, *Kw, *Vw;
    if (i & 1) { Qr = QB2; Kr = KB2; Vr = VB2; Qw = QA;  Kw = KA;  Vw = VA; }
    else       { Qr = QA;  Kr = KA;  Vr = VA;  Qw = QB2; Kw = KB2; Vw = VB2; }
    attn_mfma<<<dim3(NBS * NHH, 5), dim3(256), 0, stream>>>(Qr, Kr, Vr, Obf);
    block_step2<<<dim3(845), dim3(64), 0, stream>>>(
        Obf, WoT, bo, ln1_g, ln1_b, Wf1T, bf1, Wf2T, bf2,
        ln2_g, ln2_b, C2, W_tp2, b_tp2, WqkvT, BQKV,
        lnf_g, lnf_b, W_end, b_end, w_acl, out,
        Z, Qw, Kw, Vw, i);
  }
}

// Round 14
// 614.456 us; speedup vs baseline: 1.1476x; 1.1476x over previous
//
#include <hip/hip_runtime.h>
#include <hip/hip_bf16.h>
#include <math.h>

// Problem dims
#define BB   4
#define TT   12
#define NN   307
#define SS   11
#define HH   64
#define NHH  4
#define EMB  152
#define ROWS 13508          // B*S*N
#define NBS  44             // B*S
#define NBT  48             // B*T
#define NP   320            // padded node count
#define EP   160            // padded embedding dim
#define KLP  24             // LDS K pitch (shorts) in attn
#define VLP  336            // LDS V^T pitch (shorts) in attn
#define PLP  40             // LDS P chunk pitch (shorts) in attn
#define HCP  264            // LDS hidden chunk pitch (shorts)
#define HLP  72             // LDS h1/z chunk pitch (shorts)

typedef short short8 __attribute__((ext_vector_type(8)));   // 8 bf16
typedef short short4a __attribute__((ext_vector_type(4)));  // 4 bf16
typedef float floatx4 __attribute__((ext_vector_type(4)));
#define MFMA_B16(a, b, c) __builtin_amdgcn_mfma_f32_16x16x32_bf16(a, b, c, 0, 0, 0)

__device__ __forceinline__ float wave_sum(float v) {
#pragma unroll
  for (int off = 32; off; off >>= 1) v += __shfl_xor(v, off);
  return v;
}
__device__ __forceinline__ short f2bf(float x) {
  __hip_bfloat16 h = __float2bfloat16(x);
  return *reinterpret_cast<short*>(&h);
}

// shared transpose helper (32x32 tile, fp32 -> bf16, optional scale)
__device__ __forceinline__ void xpose_tile(
    const float* __restrict__ src, __hip_bfloat16* __restrict__ dst,
    int K, int N, int bx, int by, float scale, float (*t)[33])
{
  int k0 = bx * 32, n0 = by * 32;
  int tx = threadIdx.x & 31, ty = threadIdx.x >> 5;
#pragma unroll
  for (int i = 0; i < 32; i += 8) {
    int k = k0 + ty + i, n = n0 + tx;
    if (k < K && n < N) t[ty + i][tx] = src[(long)k * N + n];
  }
  __syncthreads();
#pragma unroll
  for (int i = 0; i < 32; i += 8) {
    int n = n0 + ty + i, k = k0 + tx;
    if (k < K && n < N)
      dst[(long)n * K + k] = __float2bfloat16(t[tx][ty + i] * scale);
  }
}

// ---------------------------------------------------------------------------
// MEGA-PREP (R13, unchanged)
// ---------------------------------------------------------------------------
__global__ __launch_bounds__(256) void prep_kernel(
    const float* __restrict__ ori, const float* __restrict__ W_val,
    const float* __restrict__ b_val, const float* __restrict__ tod_emb,
    const float* __restrict__ dow_emb, const float* __restrict__ node_emb,
    const float* __restrict__ W_in,
    const float* __restrict__ Wq, const float* __restrict__ Wk,
    const float* __restrict__ Wv, const float* __restrict__ Wo,
    const float* __restrict__ Wf1, const float* __restrict__ Wf2,
    const float* __restrict__ bq, const float* __restrict__ bk,
    const float* __restrict__ bv,
    const float* __restrict__ Wg1, const float* __restrict__ Wg2,
    const float* __restrict__ adj, const float* __restrict__ adj_sem,
    const float* __restrict__ b_in,
    const float* __restrict__ coeff2, const float* __restrict__ W_ce,
    const float* __restrict__ b_ce,
    __hip_bfloat16* __restrict__ xe, __hip_bfloat16* __restrict__ WinT,
    __hip_bfloat16* __restrict__ WqkvT, __hip_bfloat16* __restrict__ WoT,
    __hip_bfloat16* __restrict__ Wf1T, __hip_bfloat16* __restrict__ Wf2T,
    float* __restrict__ bqkv,
    __hip_bfloat16* __restrict__ WGPT,
    __hip_bfloat16* __restrict__ adjb, __hip_bfloat16* __restrict__ adjsb,
    float* __restrict__ Z, float* __restrict__ C2)
{
  __shared__ float t[32][33];
  int blk = blockIdx.x;

  if (blk < 9600) {                 // ---- embedding ----
    int idx = blk * 256 + threadIdx.x;
    int c = idx % EP;
    int r = idx / EP;               // bt*NP + node
    int node = r % NP;
    int bt = r / NP;
    float v = 0.f;
    if (node < NN && c < EMB) {
      long orr = (long)bt * NN + node;
      if (c < 24) {
        const float* x = ori + orr * 3;
        v = x[0] * W_val[c] + x[1] * W_val[24 + c] + x[2] * W_val[48 + c] + b_val[c];
      } else if (c < 48) {
        float f = ori[orr * 3 + 1];
        f = f - floorf(f);
        int tod = (int)(f * 288.f);
        tod = min(max(tod, 0), 287);
        v = tod_emb[tod * 24 + (c - 24)];
      } else if (c < 72) {
        float f = ori[orr * 3 + 2];
        f = f - floorf(f);
        int dow = (int)(f * 7.f);
        dow = min(max(dow, 0), 6);
        v = dow_emb[dow * 24 + (c - 48)];
      } else {
        v = node_emb[node * 80 + (c - 72)];
      }
    }
    xe[idx] = __float2bfloat16(v);
  } else if (blk < 10854) {         // ---- W_in transpose (57 x 22 tiles) ----
    int q = blk - 9600;
    xpose_tile(W_in, WinT, 1824, 704, q % 57, q / 57, 1.f, t);
  } else if (blk < 10903) {         // ---- small-weight transposes + bias ----
    int b2 = blk - 10854;
    if (b2 == 48) {
      int th = threadIdx.x;
      if (th < 64) {
        bqkv[th] = bq[th] * 0.25f;  // score scale folded into q
        bqkv[64 + th] = bk[th];
        bqkv[128 + th] = bv[th];
      }
      return;
    }
    const float* src; __hip_bfloat16* dst;
    int K, N, bx, by; float scale = 1.f;
    if (b2 < 4)       { src = Wq;  dst = WqkvT;           K = 64;  N = 64;  bx = b2 & 1;        by = b2 >> 1;        scale = 0.25f; }
    else if (b2 < 8)  { src = Wk;  dst = WqkvT + 64 * 64; K = 64;  N = 64;  bx = (b2 - 4) & 1;  by = (b2 - 4) >> 1; }
    else if (b2 < 12) { src = Wv;  dst = WqkvT + 128 * 64;K = 64;  N = 64;  bx = (b2 - 8) & 1;  by = (b2 - 8) >> 1; }
    else if (b2 < 16) { src = Wo;  dst = WoT;             K = 64;  N = 64;  bx = (b2 - 12) & 1; by = (b2 - 12) >> 1; }
    else if (b2 < 32) { src = Wf1; dst = Wf1T;            K = 64;  N = 256; bx = (b2 - 16) % 2; by = (b2 - 16) / 2; }
    else              { src = Wf2; dst = Wf2T;            K = 256; N = 64;  bx = (b2 - 32) % 8; by = (b2 - 32) / 8; }
    xpose_tile(src, dst, K, N, bx, by, scale, t);
  } else {                          // ---- packs + Z init + C2 ----
    int b3 = blk - 10903;
    if (b3 < 80) {
      int idx = b3 * 256 + threadIdx.x;           // < 128*160
      int c = idx / EP, k = idx % EP;
      float v = 0.f;
      if (k < EMB) v = (c < 64) ? Wg1[k * 64 + c] : Wg2[k * 64 + (c - 64)];
      WGPT[idx] = __float2bfloat16(v);
    } else if (b3 < 480) {
      int idx = (b3 - 80) * 256 + threadIdx.x;    // < 320*320
      int m = idx / NP, k = idx % NP;
      float v1 = 0.f, v2 = 0.f;
      if (m < NN && k < NN) { v1 = adj[m * NN + k]; v2 = adj_sem[m * NN + k]; }
      adjb[idx] = __float2bfloat16(v1);
      adjsb[idx] = __float2bfloat16(v2);
    } else if (b3 < 3857) {
      int idx = (b3 - 480) * 256 + threadIdx.x;   // < 1228*704
      Z[idx] = b_in[idx % 704];
    } else {
      int idx = (b3 - 3857) * 256 + threadIdx.x;  // < 13508*64
      int row = idx >> 6, h = idx & 63;           // row = (b*N+n)*S + s
      float a0 = coeff2[(long)row * 2];
      float a1 = coeff2[(long)row * 2 + 1];
      C2[idx] = a0 * W_ce[h] + a1 * W_ce[64 + h] + b_ce[h];
    }
  }
}

// ---------------------------------------------------------------------------
// xg_mfma (unchanged)
// ---------------------------------------------------------------------------
__global__ __launch_bounds__(256) void xg_mfma(
    const __hip_bfloat16* __restrict__ XE, const __hip_bfloat16* __restrict__ WGPT,
    __hip_bfloat16* __restrict__ XGT)
{
  int bt = blockIdx.x;
  int tid = threadIdx.x, w = tid >> 6, l = tid & 63;
  int m0 = blockIdx.y * 64 + w * 16;      // node tile
  int cq = l & 15, rq = l >> 4;

  short8 af[5];
  const short* Ap = (const short*)XE + ((long)bt * NP + m0 + cq) * EP + rq * 8;
#pragma unroll
  for (int kk = 0; kk < 5; ++kk) af[kk] = *(const short8*)(Ap + kk * 32);

#pragma unroll
  for (int ct = 0; ct < 8; ++ct) {
    const short* Bp = (const short*)WGPT + (long)(ct * 16 + cq) * EP + rq * 8;
    floatx4 acc = {0.f, 0.f, 0.f, 0.f};
#pragma unroll
    for (int kk = 0; kk < 5; ++kk)
      acc = MFMA_B16(af[kk], *(const short8*)(Bp + kk * 32), acc);
    short4a pk;
#pragma unroll
    for (int r = 0; r < 4; ++r) pk[r] = f2bf(acc[r]);
    *(short4a*)((short*)XGT + ((long)bt * 128 + ct * 16 + cq) * NP + m0 + rq * 4) = pk;
  }
}

// ---------------------------------------------------------------------------
// gcn_mfma (unchanged)
// ---------------------------------------------------------------------------
__global__ __launch_bounds__(256) void gcn_mfma(
    const __hip_bfloat16* __restrict__ XGT, const __hip_bfloat16* __restrict__ adjb,
    const __hip_bfloat16* __restrict__ adjsb, const float* __restrict__ bg,
    float* __restrict__ GT)
{
  int bt = blockIdx.x;
  int tid = threadIdx.x, w = tid >> 6, l = tid & 63;
  int n0 = blockIdx.y * 64;
  int cq = l & 15, rq = l >> 4;

  short8 a1[10], a2[10];
  const short* A1p = (const short*)XGT + ((long)bt * 128 + w * 16 + cq) * NP + rq * 8;
  const short* A2p = A1p + 64 * NP;
#pragma unroll
  for (int kk = 0; kk < 10; ++kk) {
    a1[kk] = *(const short8*)(A1p + kk * 32);
    a2[kk] = *(const short8*)(A2p + kk * 32);
  }

  float bgv[4];
#pragma unroll
  for (int r = 0; r < 4; ++r) bgv[r] = bg[w * 16 + rq * 4 + r];

#pragma unroll
  for (int nt = 0; nt < 4; ++nt) {
    const short* B1p = (const short*)adjb + (long)(n0 + nt * 16 + cq) * NP + rq * 8;
    const short* B2p = (const short*)adjsb + (long)(n0 + nt * 16 + cq) * NP + rq * 8;
    floatx4 acc = {0.f, 0.f, 0.f, 0.f};
#pragma unroll
    for (int kk = 0; kk < 10; ++kk) {
      acc = MFMA_B16(a1[kk], *(const short8*)(B1p + kk * 32), acc);
      acc = MFMA_B16(a2[kk], *(const short8*)(B2p + kk * 32), acc);
    }
    int node = n0 + nt * 16 + cq;
    if (node < NN) {
      float4 pk;
      pk.x = fmaxf(acc[0] + bgv[0], 0.f);
      pk.y = fmaxf(acc[1] + bgv[1], 0.f);
      pk.z = fmaxf(acc[2] + bgv[2], 0.f);
      pk.w = fmaxf(acc[3] + bgv[3], 0.f);
      *(float4*)(GT + (((long)bt * NP + node) * 64 + w * 16 + rq * 4)) = pk;
    }
  }
}

// ---------------------------------------------------------------------------
// x_in GEMM (unchanged)
// ---------------------------------------------------------------------------
__global__ __launch_bounds__(256) void gemm_xin(
    const __hip_bfloat16* __restrict__ XE, const __hip_bfloat16* __restrict__ BT,
    float* __restrict__ C)
{
  int tid = threadIdx.x, w = tid >> 6, l = tid & 63;
  int m0 = blockIdx.x * 64 + w * 16;
  int n0 = blockIdx.y * 64;
  int k0s = blockIdx.z * 480;
  int k0e = min(1824, k0s + 480);

  int cq = l & 15, rq = l >> 4;
  int arow = min(m0 + cq, 1227);
  int ab = arow / NN, an = arow - ab * NN;
  const short* Abase = (const short*)XE;
  const short* Bp = (const short*)BT + rq * 8;

  floatx4 acc[4] = {};
  for (int k0 = k0s; k0 < k0e; k0 += 32) {
    int kk = k0 + rq * 8;
    int t = kk / EMB;
    int c = kk - t * EMB;
    short8 a = *(const short8*)(Abase + (((long)(ab * TT + t)) * NP + an) * EP + c);
#pragma unroll
    for (int nt = 0; nt < 4; ++nt) {
      short8 b = *(const short8*)(Bp + (long)(n0 + nt * 16 + cq) * 1824 + k0);
      acc[nt] = MFMA_B16(a, b, acc[nt]);
    }
  }
#pragma unroll
  for (int nt = 0; nt < 4; ++nt) {
    int c = n0 + nt * 16 + cq;
#pragma unroll
    for (int r = 0; r < 4; ++r) {
      int row = m0 + rq * 4 + r;
      if (row < 1228) atomicAdd(&C[(long)row * 704 + c], acc[nt][r]);
    }
  }
}

// ---------------------------------------------------------------------------
// gp + initial QKV (R13, unchanged)
// ---------------------------------------------------------------------------
__global__ __launch_bounds__(256) void gp_qkv(
    const float* __restrict__ GT, const float* __restrict__ Wgo,
    const float* __restrict__ bgo, const float* __restrict__ w_het,
    float* __restrict__ out,
    const float* __restrict__ Z, const __hip_bfloat16* __restrict__ WT,
    const float* __restrict__ bqkv,
    __hip_bfloat16* __restrict__ Qb, __hip_bfloat16* __restrict__ Kb,
    __hip_bfloat16* __restrict__ Vtb)
{
  __shared__ float buf[4][TT * 64];
  int blk = blockIdx.x;
  if (blk < 307) {
    int wave = threadIdx.x >> 6, lane = threadIdx.x & 63;
    int bn = blk * 4 + wave;        // 307*4 = 1228 exact
    int b = bn / NN, n = bn % NN;
    float* bw = buf[wave];
    for (int idx = lane; idx < TT * 64; idx += 64) {
      int t = idx >> 6, h = idx & 63;
      bw[idx] = GT[(((long)(b * TT + t)) * NP + n) * 64 + h];
    }
    float acc[12] = {};
#pragma unroll
    for (int j = 0; j < 12; ++j) {
      int k = j * 64 + lane;
      float g = bw[k];
      const float* wr = Wgo + (long)k * 12;
#pragma unroll
      for (int o = 0; o < 12; ++o) acc[o] += g * wr[o];
    }
#pragma unroll
    for (int o = 0; o < 12; ++o) acc[o] = wave_sum(acc[o]);
    if (lane == 0) {
      float wh = w_het[0];
#pragma unroll
      for (int o = 0; o < 12; ++o)
        out[((long)b * 12 + o) * NN + n] = wh * (acc[o] + bgo[o]);
    }
  } else {
    int q = blk - 307;
    int bs = q / 5, mt = q % 5;
    int tid = threadIdx.x, w = tid >> 6, l = tid & 63;
    int m0 = mt * 64 + w * 16;
    int cq = l & 15, rq = l >> 4;
    int b = bs / SS, s = bs - b * SS;

    int node0 = m0 + cq;
    short8 a0 = {0, 0, 0, 0, 0, 0, 0, 0}, a1 = a0;
    if (node0 < NN) {
      const float* zp = Z + (((long)(b * NN + node0)) * SS + s) * 64 + rq * 8;
#pragma unroll
      for (int j = 0; j < 8; ++j) {
        a0[j] = f2bf(zp[j]);
        a1[j] = f2bf(zp[32 + j]);
      }
    }
#pragma unroll
    for (int nt = 0; nt < 12; ++nt) {
      const short* Bp = (const short*)WT + (long)(nt * 16 + cq) * 64 + rq * 8;
      floatx4 acc = {0.f, 0.f, 0.f, 0.f};
      acc = MFMA_B16(a0, *(const short8*)Bp, acc);
      acc = MFMA_B16(a1, *(const short8*)(Bp + 32), acc);
      int c = nt * 16 + cq;
      float bias = bqkv[c];
#pragma unroll
      for (int r = 0; r < 4; ++r) {
        int node = m0 + rq * 4 + r;
        if (node < NN) {
          __hip_bfloat16 v = __float2bfloat16(acc[r] + bias);
          if (c < 64)       Qb[((long)bs * NP + node) * 64 + c] = v;
          else if (c < 128) Kb[((long)bs * NP + node) * 64 + (c - 64)] = v;
          else              Vtb[((long)bs * 64 + (c - 128)) * NP + node] = v;
        }
      }
    }
  }
}

// ---------------------------------------------------------------------------
// MFMA attention (R6/R8 proven structure; 880 blocks, unchanged).
// ---------------------------------------------------------------------------
__global__ __launch_bounds__(256) void attn_mfma(
    const __hip_bfloat16* __restrict__ Qb, const __hip_bfloat16* __restrict__ Kb,
    const __hip_bfloat16* __restrict__ Vtb, __hip_bfloat16* __restrict__ O)
{
  int bsh = blockIdx.x;           // bs*NH + head
  int head = bsh & 3;
  int bs = bsh >> 2;

  __shared__ __align__(16) short Kl[NP * KLP];
  __shared__ __align__(16) short Vl[16 * VLP];
  __shared__ __align__(16) short Pd[4][2][16 * PLP];

  int tid = threadIdx.x;
  const short* kg = (const short*)Kb + (long)bs * NP * 64 + head * 16;
  for (int ch = tid; ch < NP * 4; ch += 256) {
    int node = ch >> 2, part = (ch & 3) * 4;
    short4a kv = {0, 0, 0, 0};
    if (node < NN) kv = *(const short4a*)(kg + (long)node * 64 + part);
    *(short4a*)&Kl[node * KLP + part] = kv;
  }
  const short* vg = (const short*)Vtb + ((long)bs * 64 + head * 16) * NP;
  for (int ch = tid; ch < 16 * 80; ch += 256) {
    int d = ch / 80, k4 = (ch % 80) * 4;
    short4a vv = {0, 0, 0, 0};
    if (k4 + 3 < NN) {
      vv = *(const short4a*)(vg + (long)d * NP + k4);
    } else {
#pragma unroll
      for (int j = 0; j < 4; ++j)
        if (k4 + j < NN) vv[j] = vg[(long)d * NP + k4 + j];
    }
    *(short4a*)&Vl[d * VLP + k4] = vv;
  }
  __syncthreads();

  int wave = tid >> 6, lane = tid & 63;
  int m = lane & 15, quad = lane >> 4;
  int gg = blockIdx.y * 4 + wave;     // 16-query group, 0..19
  int q0 = gg * 16;
  int qv = q0 + m;

  const short8 z8 = {0, 0, 0, 0, 0, 0, 0, 0};
  const floatx4 zf = {0.f, 0.f, 0.f, 0.f};

  short8 qf = z8;
  if (quad < 2 && qv < NN)
    qf = *(const short8*)((const short*)Qb +
        ((long)bs * NP + qv) * 64 + head * 16 + quad * 8);

  short* Pw0 = &Pd[wave][0][0];
  short* Pw1 = &Pd[wave][1][0];

  float sum = 0.f;
  floatx4 oa = zf, ob = zf;

  for (int c = 0; c < 10; ++c) {
    short8 kf0 = z8, kf1 = z8;
    if (quad < 2) {
      kf0 = *(const short8*)&Kl[((2 * c) * 16 + m) * KLP + quad * 8];
      kf1 = *(const short8*)&Kl[((2 * c + 1) * 16 + m) * KLP + quad * 8];
    }
    floatx4 s0 = MFMA_B16(kf0, qf, zf);
    floatx4 s1 = MFMA_B16(kf1, qf, zf);

    float e0[4], e1[4];
#pragma unroll
    for (int j = 0; j < 4; ++j) {
      e0[j] = __expf(fminf(s0[j], 30.f));
      e1[j] = __expf(fminf(s1[j], 30.f));
    }
    if (c == 9) {
      if (quad == 0) e1[3] = 0.f;
      else { e1[0] = 0.f; e1[1] = 0.f; e1[2] = 0.f; e1[3] = 0.f; }
    }
    sum += e0[0] + e0[1] + e0[2] + e0[3] + e1[0] + e1[1] + e1[2] + e1[3];

    short4a p0, p1;
#pragma unroll
    for (int j = 0; j < 4; ++j) { p0[j] = f2bf(e0[j]); p1[j] = f2bf(e1[j]); }
    short* Pw = (c & 1) ? Pw1 : Pw0;
    *(short4a*)&Pw[m * PLP + quad * 4] = p0;
    *(short4a*)&Pw[m * PLP + 16 + quad * 4] = p1;

    short8 pf = *(const short8*)&Pw[m * PLP + quad * 8];
    short8 vf = *(const short8*)&Vl[m * VLP + c * 32 + quad * 8];
    if (c & 1) ob = MFMA_B16(vf, pf, ob);
    else       oa = MFMA_B16(vf, pf, oa);
  }

  sum += __shfl_xor(sum, 16);
  sum += __shfl_xor(sum, 32);
  float inv = 1.f / sum;

  if (qv < NN) {
    short4a pk;
#pragma unroll
    for (int r = 0; r < 4; ++r) pk[r] = f2bf((oa[r] + ob[r]) * inv);
    *(short4a*)((short*)O + ((long)bs * NN + qv) * 64 + head * 16 + quad * 4) = pk;
  }
}

// ---------------------------------------------------------------------------
// block_step3: 256 threads, 4 waves per 16-row tile (col-split across waves).
// wave w owns cols w*16..w*16+15 for Wo/FFN-B/Euler, ht tiles 4w..4w+3 for
// FFN-A, nt tiles 3w..3w+2 for QKV. LNs use wave partials + LDS Red combine.
// ---------------------------------------------------------------------------
__global__ __launch_bounds__(256) void block_step3(
    const __hip_bfloat16* __restrict__ A, const __hip_bfloat16* __restrict__ WoT,
    const float* __restrict__ bo, const float* __restrict__ ln1g,
    const float* __restrict__ ln1b,
    const __hip_bfloat16* __restrict__ Wf1T, const float* __restrict__ bf1,
    const __hip_bfloat16* __restrict__ Wf2T, const float* __restrict__ bf2,
    const float* __restrict__ ln2g, const float* __restrict__ ln2b,
    const float* __restrict__ C2, const float* __restrict__ W_tp2,
    const float* __restrict__ b_tp2,
    const __hip_bfloat16* __restrict__ WqkvT, const float* __restrict__ bqkv,
    const float* __restrict__ lnf_g, const float* __restrict__ lnf_b,
    const float* __restrict__ W_end, const float* __restrict__ b_end,
    const float* __restrict__ w_acl, float* __restrict__ out,
    float* __restrict__ Z,
    __hip_bfloat16* __restrict__ Qn, __hip_bfloat16* __restrict__ Kn,
    __hip_bfloat16* __restrict__ Vtn, int iter)
{
  __shared__ __align__(16) short Hl[16 * HLP];   // h1 / zn chunk (full rows)
  __shared__ __align__(16) short Hc[16 * HCP];   // hidden chunk
  __shared__ float Red[4][16];                   // per-wave row partials
  __shared__ float Fin[12][4][16];               // final-head partials

  int tid = threadIdx.x;
  int w = tid >> 6, l = tid & 63;
  int cq = l & 15, rq = l >> 4;
  int m0 = blockIdx.x * 16;
  int col = w * 16 + cq;

  // ---- Wo GEMM (wave's col tile) ----
  const short* Ap = (const short*)A + (long)(m0 + cq) * 64 + rq * 8;
  short8 a0 = *(const short8*)Ap;
  short8 a1 = *(const short8*)(Ap + 32);
  {
  }
  const short* Bp0 = (const short*)WoT + (long)col * 64 + rq * 8;
  floatx4 acc0 = {0.f, 0.f, 0.f, 0.f};
  acc0 = MFMA_B16(a0, *(const short8*)Bp0, acc0);
  acc0 = MFMA_B16(a1, *(const short8*)(Bp0 + 32), acc0);
  float bov = bo[col];
  float x[4];
#pragma unroll
  for (int r = 0; r < 4; ++r) x[r] = acc0[r] + bov;

  // row metadata (clamped for tail rows)
  int rows[4]; bool val[4]; long zov[4]; int s1v[4]; long bnv[4];
#pragma unroll
  for (int r = 0; r < 4; ++r) {
    rows[r] = m0 + rq * 4 + r;
    val[r] = rows[r] < ROWS;
    int rc = min(rows[r], ROWS - 1);
    int bs = rc / NN, node = rc - bs * NN;
    int b = bs / SS;
    s1v[r] = bs - b * SS;
    bnv[r] = (long)b * NN + node;
    zov[r] = (bnv[r] * SS + s1v[r]) * 64;
    x[r] += Z[zov[r] + col];
  }
  float g1 = ln1g[col], b1 = ln1b[col];
  float g2 = ln2g[col], b2 = ln2b[col];
  float f2 = bf2[col];

  // ---- LN1 (wave partial over 16 cols -> Red combine) ----
  float mean[4], rstd[4];
  {
    float p[4];
#pragma unroll
    for (int r = 0; r < 4; ++r) {
      float s = x[r];
#pragma unroll
      for (int o2 = 1; o2 <= 8; o2 <<= 1) s += __shfl_xor(s, o2);
      p[r] = s;
    }
    if (cq == 0) {
#pragma unroll
      for (int r = 0; r < 4; ++r) Red[w][rq * 4 + r] = p[r];
    }
    __syncthreads();
#pragma unroll
    for (int r = 0; r < 4; ++r) {
      int rr = rq * 4 + r;
      mean[r] = (Red[0][rr] + Red[1][rr] + Red[2][rr] + Red[3][rr]) * (1.f / 64.f);
    }
    __syncthreads();
#pragma unroll
    for (int r = 0; r < 4; ++r) {
      float d = x[r] - mean[r];
      float s = d * d;
#pragma unroll
      for (int o2 = 1; o2 <= 8; o2 <<= 1) s += __shfl_xor(s, o2);
      p[r] = s;
    }
    if (cq == 0) {
#pragma unroll
      for (int r = 0; r < 4; ++r) Red[w][rq * 4 + r] = p[r];
    }
    __syncthreads();
#pragma unroll
    for (int r = 0; r < 4; ++r) {
      int rr = rq * 4 + r;
      float vs = Red[0][rr] + Red[1][rr] + Red[2][rr] + Red[3][rr];
      rstd[r] = rsqrtf(vs * (1.f / 64.f) + 1e-5f);
    }
  }
  float h1r[4];
#pragma unroll
  for (int r = 0; r < 4; ++r) {
    float h = (x[r] - mean[r]) * rstd[r] * g1 + b1;
    h1r[r] = h;
    Hl[(rq * 4 + r) * HLP + col] = f2bf(h);
  }
  __syncthreads();   // Hl complete (also orders Red reads before next writes)

  // ---- FFN A: wave computes ht tiles 4w..4w+3 ----
  short8 ha0 = *(const short8*)&Hl[cq * HLP + rq * 8];
  short8 ha1 = *(const short8*)&Hl[cq * HLP + 32 + rq * 8];
#pragma unroll
  for (int j = 0; j < 4; ++j) {
    int ht = w * 4 + j;
    const short* Bq = (const short*)Wf1T + (long)(ht * 16 + cq) * 64 + rq * 8;
    floatx4 ac = {0.f, 0.f, 0.f, 0.f};
    ac = MFMA_B16(ha0, *(const short8*)Bq, ac);
    ac = MFMA_B16(ha1, *(const short8*)(Bq + 32), ac);
    float bv = bf1[ht * 16 + cq];
#pragma unroll
    for (int r = 0; r < 4; ++r)
      Hc[(rq * 4 + r) * HCP + ht * 16 + cq] = f2bf(fmaxf(ac[r] + bv, 0.f));
  }
  __syncthreads();

  // ---- FFN B: wave's col tile ----
  {
    const short* Bq = (const short*)Wf2T + (long)col * 256 + rq * 8;
    floatx4 ac = {0.f, 0.f, 0.f, 0.f};
#pragma unroll
    for (int kk = 0; kk < 8; ++kk) {
      short8 pf = *(const short8*)&Hc[cq * HCP + kk * 32 + rq * 8];
      ac = MFMA_B16(pf, *(const short8*)(Bq + kk * 32), ac);
    }
#pragma unroll
    for (int r = 0; r < 4; ++r) x[r] = h1r[r] + ac[r] + f2;
  }
  __syncthreads();   // all Hc reads done; Red safe to reuse

  // ---- LN2 ----
  {
    float p[4];
#pragma unroll
    for (int r = 0; r < 4; ++r) {
      float s = x[r];
#pragma unroll
      for (int o2 = 1; o2 <= 8; o2 <<= 1) s += __shfl_xor(s, o2);
      p[r] = s;
    }
    if (cq == 0) {
#pragma unroll
      for (int r = 0; r < 4; ++r) Red[w][rq * 4 + r] = p[r];
    }
    __syncthreads();
#pragma unroll
    for (int r = 0; r < 4; ++r) {
      int rr = rq * 4 + r;
      mean[r] = (Red[0][rr] + Red[1][rr] + Red[2][rr] + Red[3][rr]) * (1.f / 64.f);
    }
    __syncthreads();
#pragma unroll
    for (int r = 0; r < 4; ++r) {
      float d = x[r] - mean[r];
      float s = d * d;
#pragma unroll
      for (int o2 = 1; o2 <= 8; o2 <<= 1) s += __shfl_xor(s, o2);
      p[r] = s;
    }
    if (cq == 0) {
#pragma unroll
      for (int r = 0; r < 4; ++r) Red[w][rq * 4 + r] = p[r];
    }
    __syncthreads();
#pragma unroll
    for (int r = 0; r < 4; ++r) {
      int rr = rq * 4 + r;
      float vs = Red[0][rr] + Red[1][rr] + Red[2][rr] + Red[3][rr];
      rstd[r] = rsqrtf(vs * (1.f / 64.f) + 1e-5f);
    }
  }

  // ---- tanh + Euler update (wave's cols only) ----
#pragma unroll
  for (int r = 0; r < 4; ++r) {
    float t = tanhf((x[r] - mean[r]) * rstd[r] * g2 + b2);
    float accw = b_tp2[s1v[r] * SS + iter];
#pragma unroll
    for (int s2 = 0; s2 < SS; ++s2)
      accw += C2[(bnv[r] * SS + s2) * 64 + col] *
              W_tp2[s2 * (SS * SS) + s1v[r] * SS + iter];
    if (val[r]) {
      float zn = Z[zov[r] + col] + t * accw;
      Z[zov[r] + col] = zn;
      Hl[(rq * 4 + r) * HLP + col] = f2bf(zn);
      x[r] = zn;
    }
  }
  __syncthreads();   // zn chunk complete

  if (iter < SS - 1) {
    // ---- QKV for next iter: wave does nt tiles 3w..3w+2 ----
    short8 za0 = *(const short8*)&Hl[cq * HLP + rq * 8];
    short8 za1 = *(const short8*)&Hl[cq * HLP + 32 + rq * 8];
#pragma unroll
    for (int j = 0; j < 3; ++j) {
      int nt = w * 3 + j;
      const short* Bq = (const short*)WqkvT + (long)(nt * 16 + cq) * 64 + rq * 8;
      floatx4 ac = {0.f, 0.f, 0.f, 0.f};
      ac = MFMA_B16(za0, *(const short8*)Bq, ac);
      ac = MFMA_B16(za1, *(const short8*)(Bq + 32), ac);
      int c = nt * 16 + cq;
      float bias = bqkv[c];
#pragma unroll
      for (int r = 0; r < 4; ++r) {
        int row = m0 + rq * 4 + r;
        if (row < ROWS) {
          int bs = row / NN;
          int node = row - bs * NN;
          __hip_bfloat16 v = __float2bfloat16(ac[r] + bias);
          if (c < 64)       Qn[((long)bs * NP + node) * 64 + c] = v;
          else if (c < 128) Kn[((long)bs * NP + node) * 64 + (c - 64)] = v;
          else              Vtn[((long)bs * 64 + (c - 128)) * NP + node] = v;
        }
      }
    }
  } else {
    // ---- final: zT = LN(zn; lnf); out += w_acl*(zT@W_end + b_end) ----
    {
      float p[4];
#pragma unroll
      for (int r = 0; r < 4; ++r) {
        float s = x[r];
#pragma unroll
        for (int o2 = 1; o2 <= 8; o2 <<= 1) s += __shfl_xor(s, o2);
        p[r] = s;
      }
      if (cq == 0) {
#pragma unroll
        for (int r = 0; r < 4; ++r) Red[w][rq * 4 + r] = p[r];
      }
      __syncthreads();
#pragma unroll
      for (int r = 0; r < 4; ++r) {
        int rr = rq * 4 + r;
        mean[r] = (Red[0][rr] + Red[1][rr] + Red[2][rr] + Red[3][rr]) * (1.f / 64.f);
      }
      __syncthreads();
#pragma unroll
      for (int r = 0; r < 4; ++r) {
        float d = x[r] - mean[r];
        float s = d * d;
#pragma unroll
        for (int o2 = 1; o2 <= 8; o2 <<= 1) s += __shfl_xor(s, o2);
        p[r] = s;
      }
      if (cq == 0) {
#pragma unroll
        for (int r = 0; r < 4; ++r) Red[w][rq * 4 + r] = p[r];
      }
      __syncthreads();
#pragma unroll
      for (int r = 0; r < 4; ++r) {
        int rr = rq * 4 + r;
        float vs = Red[0][rr] + Red[1][rr] + Red[2][rr] + Red[3][rr];
        rstd[r] = rsqrtf(vs * (1.f / 64.f) + 1e-5f);
      }
    }
    float gf = lnf_g[col], bff = lnf_b[col];
    float zT[4];
#pragma unroll
    for (int r = 0; r < 4; ++r)
      zT[r] = (x[r] - mean[r]) * rstd[r] * gf + bff;
#pragma unroll
    for (int o = 0; o < 12; ++o) {
      float pr[4];
#pragma unroll
      for (int r = 0; r < 4; ++r) {
        float p = zT[r] * W_end[col * 12 + o];
#pragma unroll
        for (int o2 = 1; o2 <= 8; o2 <<= 1) p += __shfl_xor(p, o2);
        pr[r] = p;
      }
      if (cq == 0) {
#pragma unroll
        for (int r = 0; r < 4; ++r) Fin[o][w][rq * 4 + r] = pr[r];
      }
    }
    __syncthreads();
    if (w == 0 && l < 16) {
      int row = m0 + l;
      if (row < ROWS) {
        int bs = row / NN;
        if (bs % SS == SS - 1) {
          int node = row - bs * NN;
          int b = bs / SS;
          float wa = w_acl[0];
#pragma unroll
          for (int o = 0; o < 12; ++o) {
            float p = Fin[o][0][l] + Fin[o][1][l] + Fin[o][2][l] + Fin[o][3][l];
            long oi = ((long)b * 12 + o) * NN + node;
            out[oi] = out[oi] + wa * (p + b_end[o]);
          }
        }
      }
    }
  }
}

// ---------------------------------------------------------------------------
extern "C" void kernel_launch(void* const* d_in, const int* in_sizes, int n_in,
                              void* d_out, int out_size, void* d_ws, size_t ws_size,
                              hipStream_t stream)
{
  (void)in_sizes; (void)n_in; (void)out_size; (void)ws_size;

  const float* ori_x    = (const float*)d_in[0];
  const float* coeff2   = (const float*)d_in[2];
  const float* W_val    = (const float*)d_in[5];
  const float* b_val    = (const float*)d_in[6];
  const float* tod_emb  = (const float*)d_in[7];
  const float* dow_emb  = (const float*)d_in[8];
  const float* node_emb = (const float*)d_in[9];
  const float* W_in     = (const float*)d_in[10];
  const float* b_in     = (const float*)d_in[11];
  const float* W_ce     = (const float*)d_in[12];
  const float* b_ce     = (const float*)d_in[13];
  const float* W_tp2    = (const float*)d_in[14];
  const float* b_tp2    = (const float*)d_in[15];
  const float* Wq = (const float*)d_in[20];
  const float* Wk = (const float*)d_in[21];
  const float* Wv = (const float*)d_in[22];
  const float* Wo = (const float*)d_in[23];
  const float* bq = (const float*)d_in[24];
  const float* bk = (const float*)d_in[25];
  const float* bv = (const float*)d_in[26];
  const float* bo = (const float*)d_in[27];
  const float* ln1_g = (const float*)d_in[28];
  const float* ln1_b = (const float*)d_in[29];
  const float* Wf1   = (const float*)d_in[30];
  const float* bf1   = (const float*)d_in[31];
  const float* Wf2   = (const float*)d_in[32];
  const float* bf2   = (const float*)d_in[33];
  const float* ln2_g = (const float*)d_in[34];
  const float* ln2_b = (const float*)d_in[35];
  const float* lnf_g = (const float*)d_in[36];
  const float* lnf_b = (const float*)d_in[37];
  const float* W_end = (const float*)d_in[38];
  const float* b_end = (const float*)d_in[39];
  const float* w_acl = (const float*)d_in[40];
  const float* w_het = (const float*)d_in[41];
  const float* adj     = (const float*)d_in[42];
  const float* adj_sem = (const float*)d_in[43];
  const float* Wg1 = (const float*)d_in[44];
  const float* Wg2 = (const float*)d_in[45];
  const float* bg  = (const float*)d_in[46];
  const float* Wgo = (const float*)d_in[47];
  const float* bgo = (const float*)d_in[48];
  float* out = (float*)d_out;
  float* ws  = (float*)d_ws;

  const int QSET = 450560;            // floats per Q/K/V tensor (44*320*64 bf16)

  // ---- workspace layout (float offsets, 16-float aligned) ----
  float* Z  = ws;                                // 864512
  float* C2 = ws + 864512;                       // 864512
  __hip_bfloat16* WinT  = (__hip_bfloat16*)(ws + 1729024);   // 704*1824 bf16
  __hip_bfloat16* WqkvT = (__hip_bfloat16*)(ws + 2371072);   // 192*64
  __hip_bfloat16* WoT   = (__hip_bfloat16*)(ws + 2377216);   // 64*64
  __hip_bfloat16* Wf1T  = (__hip_bfloat16*)(ws + 2379264);   // 256*64
  __hip_bfloat16* Wf2T  = (__hip_bfloat16*)(ws + 2387456);   // 64*256
  float* BQKV = ws + 2395648;                    // 192 (+pad)
  // double-buffered QKV sets
  __hip_bfloat16* QA  = (__hip_bfloat16*)(ws + 2395856);
  __hip_bfloat16* KA  = (__hip_bfloat16*)(ws + 2395856 + QSET);
  __hip_bfloat16* VA  = (__hip_bfloat16*)(ws + 2395856 + 2 * QSET);
  __hip_bfloat16* QB2 = (__hip_bfloat16*)(ws + 2395856 + 3 * QSET);
  __hip_bfloat16* KB2 = (__hip_bfloat16*)(ws + 2395856 + 4 * QSET);
  __hip_bfloat16* VB2 = (__hip_bfloat16*)(ws + 2395856 + 5 * QSET);
  float* POOL = ws + 2395856 + 6 * QSET;         // = ws + 5099216
  // phase 1
  __hip_bfloat16* XEMBb = (__hip_bfloat16*)POOL;             // 48*320*160
  __hip_bfloat16* XGT   = (__hip_bfloat16*)(POOL + 1228800); // 48*128*320
  float* GT             = POOL + 2211840;                    // 48*320*64 fp32
  __hip_bfloat16* ADJB  = (__hip_bfloat16*)(POOL + 3194880); // 320*320
  __hip_bfloat16* ADJSB = (__hip_bfloat16*)(POOL + 3246080); // 320*320
  __hip_bfloat16* WGPT  = (__hip_bfloat16*)(POOL + 3297280); // 128*160
  // phase 2 (overlays phase 1)
  __hip_bfloat16* Obf   = (__hip_bfloat16*)POOL;             // 13568*64

  // ---- phase 1: 5 dispatches ----
  prep_kernel<<<dim3(18137), dim3(256), 0, stream>>>(
      ori_x, W_val, b_val, tod_emb, dow_emb, node_emb, W_in,
      Wq, Wk, Wv, Wo, Wf1, Wf2, bq, bk, bv,
      Wg1, Wg2, adj, adj_sem, b_in, coeff2, W_ce, b_ce,
      XEMBb, WinT, WqkvT, WoT, Wf1T, Wf2T, BQKV,
      WGPT, ADJB, ADJSB, Z, C2);
  gemm_xin<<<dim3(20, 11, 4), dim3(256), 0, stream>>>(XEMBb, WinT, Z);
  xg_mfma<<<dim3(NBT, 5), dim3(256), 0, stream>>>(XEMBb, WGPT, XGT);
  gcn_mfma<<<dim3(NBT, 5), dim3(256), 0, stream>>>(XGT, ADJB, ADJSB, bg, GT);
  gp_qkv<<<dim3(527), dim3(256), 0, stream>>>(
      GT, Wgo, bgo, w_het, out, Z, WqkvT, BQKV, QA, KA, VA);

  // ---- phase 2: Euler scan, 2 dispatches per step (final fused in last) ----
  for (int i = 0; i < SS; ++i) {
    __hip_bfloat16 *Qr, *Kr, *Vr, *Qw, *Kw, *Vw;
    if (i & 1) { Qr = QB2; Kr = KB2; Vr = VB2; Qw = QA;  Kw = KA;  Vw = VA; }
    else       { Qr = QA;  Kr = KA;  Vr = VA;  Qw = QB2; Kw = KB2; Vw = VB2; }
    attn_mfma<<<dim3(NBS * NHH, 5), dim3(256), 0, stream>>>(Qr, Kr, Vr, Obf);
    block_step3<<<dim3(845), dim3(256), 0, stream>>>(
        Obf, WoT, bo, ln1_g, ln1_b, Wf1T, bf1, Wf2T, bf2,
        ln2_g, ln2_b, C2, W_tp2, b_tp2, WqkvT, BQKV,
        lnf_g, lnf_b, W_end, b_end, w_acl, out,
        Z, Qw, Kw, Vw, i);
  }
}